// Round 16
// baseline (120.521 us; speedup 1.0000x reference)
//
#include <hip/hip_runtime.h>

#define N_PTS  20000
#define NG     128                  // grid NG x NG over [-6,6]^2
#define NC     (NG * NG)            // 16384 cells per cloud
#define GMIN   (-6.0f)
#define GINV   (NG / 12.0f)
#define MARGIN 5e-4f                // >> 2e-5 worst-case |P_np - d_true^2|
#define SSTRIDE (N_PTS / 64)        // 312; 63*312 = 19656 < 20000
#define WINCAP 2048                 // staged-window cap (32 KB LDS)
#define QPB    8                    // queries per block (20000 % 8 == 0)
#define QB79   79                  // fallback

// ---- numpy-exact helpers (proven rounds 2/5/9/10/11/14) ----
__device__ __forceinline__ float np_self_dot(float x, float y, float z) {
    return __fadd_rn(__fadd_rn(__fmul_rn(x, x), __fmul_rn(y, y)),
                     __fmul_rn(z, z));
}
__device__ __forceinline__ unsigned ordmap(float f) {
    unsigned b = __float_as_uint(f);
    return (b & 0x80000000u) ? ~b : (b | 0x80000000u);
}
__device__ __forceinline__ float invord(unsigned h) {
    return __uint_as_float((h & 0x80000000u) ? (h ^ 0x80000000u) : ~h);
}
__device__ __forceinline__ int cellC(float v) {
    int c = (int)((v - GMIN) * GINV);
    return c < 0 ? 0 : (c > NG - 1 ? NG - 1 : c);
}
__device__ __forceinline__ unsigned long long wave_min_u64(unsigned long long k) {
    #pragma unroll
    for (int m = 1; m < 64; m <<= 1) {
        unsigned long long o = __shfl_xor(k, m, 64);
        k = (o < k) ? o : k;
    }
    return k;
}
__device__ __forceinline__ int imin2(int a, int b) { return a < b ? a : b; }
__device__ __forceinline__ int imax2(int a, int b) { return a > b ? a : b; }

// Single-query evaluation (bit-identical numerics to r9-r29):
// numpy-exact P; key=(ordmap(P)<<32|idx).
#define EVALQ(r, QX, QY, QZ, SQ, KEY)                                      \
    {   float sr = np_self_dot((r).x, (r).y, (r).z);                       \
        float zz = __fadd_rn(__fadd_rn(__fmul_rn(QX, (r).x),               \
                                       __fmul_rn(QY, (r).y)),              \
                             __fmul_rn(QZ, (r).z));                        \
        float P  = __fsub_rn(__fadd_rn(SQ, sr), __fadd_rn(zz, zz));        \
        unsigned long long kk =                                            \
            ((unsigned long long)ordmap(P) << 32) | __float_as_uint((r).w);\
        KEY = (kk < KEY) ? kk : KEY; }

// Process <=32 rows whose bounds sit in register BND (lanes 0..31 = row
// starts, lanes 32..63 = row ends): triples via shfl, flat 3-interval
// stream, 2-deep pipelined. (r23/r28/r29 PROVEN machinery.)
#define SCAN_ROWS32(BND, ROWS, QX, QY, QZ, SQ, KEY)                        \
    for (int r0 = 0; r0 < (ROWS); r0 += 3) {                               \
        int i1 = r0 + 1 < (ROWS) ? r0 + 1 : (ROWS) - 1;                    \
        int i2 = r0 + 2 < (ROWS) ? r0 + 2 : (ROWS) - 1;                    \
        int L0 = __shfl(BND, r0, 64), H0 = __shfl(BND, 32 + r0, 64);       \
        int L1 = __shfl(BND, i1, 64), H1 = __shfl(BND, 32 + i1, 64);       \
        int L2 = __shfl(BND, i2, 64), H2 = __shfl(BND, 32 + i2, 64);       \
        int d0 = H0 - L0;                                                  \
        int d1 = (r0 + 1 < (ROWS)) ? H1 - L1 : 0;                          \
        int d2 = (r0 + 2 < (ROWS)) ? H2 - L2 : 0;                          \
        int s01 = d0 + d1, tot = s01 + d2;                                 \
        int t = lane;                                                      \
        if (t < tot) {                                                     \
            int p = t < d0 ? L0 + t : t < s01 ? L1 + (t - d0)              \
                                              : L2 + (t - s01);            \
            float4 rc = rs[p];                                             \
            for (t += 64; t < tot; t += 64) {                              \
                int pn = t < d0 ? L0 + t : t < s01 ? L1 + (t - d0)         \
                                                   : L2 + (t - s01);       \
                float4 rn = rs[pn];                                        \
                EVALQ(rc, QX, QY, QZ, SQ, KEY)                             \
                rc = rn;                                                   \
            }                                                              \
            EVALQ(rc, QX, QY, QZ, SQ, KEY)                                 \
        }                                                                  \
    }

// General rect scan from L2 (certification path; r23/r28/r29 PROVEN).
#define SCAN_RECT(xL, xR, yL, yR, QX, QY, QZ, SQ, KEY)                     \
    {   int R = (xR) - (xL) + 1;                                           \
        for (int g = 0; g < R; g += 32) {                                  \
            int rows = R - g; if (rows > 32) rows = 32;                    \
            int xr  = (xL) + g + (l31 < rows ? l31 : rows - 1);            \
            int col = (lane < 32) ? (yL) : ((yR) + 1);                     \
            int b2 = cs[xr * NG + col];                                    \
            SCAN_ROWS32(b2, rows, QX, QY, QZ, SQ, KEY)                     \
        }                                                                  \
    }

// ---- build A1 (r16/r18, PROVEN): wide parallel histogram, global atomics ----
__global__ __launch_bounds__(256) void k_hist(
    const float* __restrict__ preds, const float* __restrict__ gts,
    int* __restrict__ cursor)
{
    int t = blockIdx.x * 256 + threadIdx.x;
    if (t >= 2 * N_PTS) return;
    int cl = t / N_PTS, i = t - cl * N_PTS;
    const float* src = cl ? gts : preds;
    int cell = cellC(src[i*3+0]) * NG + cellC(src[i*3+1]);
    atomicAdd(&cursor[cl * NC + cell], 1);
}

// ---- build A2 (r22, PROVEN): scan via shfl wave-scans, 2 barriers ----
__global__ __launch_bounds__(1024) void k_scan(
    int* __restrict__ cursor, int* __restrict__ bstart)
{
    __shared__ int wsum[16];
    __shared__ int wpre[16];
    int cl = blockIdx.x, t = threadIdx.x;
    int wave = t >> 6, lane = t & 63;

    int base = cl * NC + t * 16;                    // 64B-aligned (ws layout)
    const int4* c4 = (const int4*)(cursor + base);
    int4 a = c4[0], b = c4[1], c = c4[2], d = c4[3];
    int v[16] = { a.x, a.y, a.z, a.w, b.x, b.y, b.z, b.w,
                  c.x, c.y, c.z, c.w, d.x, d.y, d.z, d.w };
    int s = 0;
    #pragma unroll
    for (int i = 0; i < 16; ++i) s += v[i];

    int ps = s;                                     // inclusive 64-lane scan
    #pragma unroll
    for (int m = 1; m < 64; m <<= 1) {
        int o = __shfl_up(ps, m, 64);
        if (lane >= m) ps += o;
    }
    if (lane == 63) wsum[wave] = ps;
    __syncthreads();
    if (t < 16) {
        int x = wsum[t];
        int px = x;                                 // inclusive 16-scan
        #pragma unroll
        for (int m = 1; m < 16; m <<= 1) {
            int o = __shfl_up(px, m, 16);
            if ((t & 15) >= m) px += o;
        }
        wpre[t] = px - x;                           // exclusive wave prefix
    }
    __syncthreads();

    int run = wpre[wave] + (ps - s);                // exclusive thread prefix
    #pragma unroll
    for (int i = 0; i < 16; ++i) {
        bstart[cl * (NC + 1) + t * 16 + i] = run;
        cursor[base + i] = run;
        run += v[i];
    }
    if (t == 1023) bstart[cl * (NC + 1) + NC] = run;   // == N_PTS
}

// ---- build B (r15/r18, PROVEN): wide scatter into cell-sorted order ----
__global__ __launch_bounds__(256) void k_scatter(
    const float* __restrict__ preds, const float* __restrict__ gts,
    int* __restrict__ cursor, float4* __restrict__ sorted)
{
    int t = blockIdx.x * 256 + threadIdx.x;
    if (t >= 2 * N_PTS) return;
    int cl = t / N_PTS, i = t - cl * N_PTS;
    const float* src = cl ? gts : preds;
    float x = src[i*3+0], y = src[i*3+1], z = src[i*3+2];
    int cell = cellC(x) * NG + cellC(y);
    int pos = atomicAdd(&cursor[cl * NC + cell], 1);
    sorted[(size_t)cl * N_PTS + pos] = make_float4(x, y, z, __int_as_float(i));
}

// ---- main (r30): LDS-staged shared window, 8 queries per 256-thr block.
// r23/r26/r28/r29 invariance (k_main ~50-52us under wave count x0.25-1,
// work x1-5, 1-2 q/wave) => the governor is per-QUERY serial L2 chains.
// r30 amortizes the chain across 8 consecutive cell-sorted queries:
// stage the y-clipped UNION box of their 5x5 seeds into LDS ONCE
// (block-coop coalesced), then each of 4 waves evals the window from LDS
// (one read, two EVALs) for its 2 sequential queries (r29-proven shape).
// ~0.4 serial L2 trips/query (was ~3-5). Certification per query
// unchanged: W-box inside staged box (common; box built from +-2, W~+-2)
// else exact SCAN_RECT from L2 (r28/r29 machinery; rescans idempotent).
// Block-uniform fallbacks: window overflow (>WINCAP pts or >32 rows,
// ~1% row-wrap blocks) -> r29's exact per-wave path; off==0 -> samp.
// All evaluated points are genuine candidates; keys/tie-break identical
// => bit-identical outputs (numpy-exact P; key=(ordmap(P)<<32|idx);
// wave-min == numpy first-occurrence argmin; W^2 = d_seed + MARGIN).
__global__ __launch_bounds__(256) void k_main(
    const float4* __restrict__ sorted, const int* __restrict__ bstart,
    float* __restrict__ out)
{
    __shared__ float4 win[WINCAP];              // 32 KB
    __shared__ float4 qbuf[QPB];

    int bid  = blockIdx.x;                      // 0..4999
    int tid  = threadIdx.x;
    int wave = tid >> 6, lane = tid & 63, l31 = lane & 31;
    int q0   = bid * QPB;
    int dir  = q0 / N_PTS;                      // block same dir (20000%8==0)
    int qp0  = q0 - dir * N_PTS;
    int rcl  = 1 - dir;

    const float4* rs = sorted + (size_t)rcl * N_PTS;
    const int*    cs = bstart + rcl * (NC + 1);

    if (tid < QPB) qbuf[tid] = sorted[(size_t)dir * N_PTS + qp0 + tid];
    __syncthreads();

    // union box of the 8 queries' 5x5 seed boxes (wave-uniform)
    int mnx = NG, mxx = -1, mny = NG, mxy = -1;
    #pragma unroll
    for (int j = 0; j < QPB; ++j) {
        float4 q = qbuf[j];
        int cx = cellC(q.x), cy = cellC(q.y);
        mnx = imin2(mnx, cx); mxx = imax2(mxx, cx);
        mny = imin2(mny, cy); mxy = imax2(mxy, cy);
    }
    int xL = imax2(mnx - 2, 0), xR = imin2(mxx + 2, NG - 1);
    int yL = imax2(mny - 2, 0), yR = imin2(mxy + 2, NG - 1);
    int R  = xR - xL + 1;

    // per-wave bounds load (identical addresses in all waves -> same bnd)
    int xr  = xL + (l31 < R ? l31 : R - 1);
    int col = (lane < 32) ? yL : (yR + 1);
    int bnd = (R <= 32) ? cs[xr * NG + col] : 0;

    int total = 0;
    if (R <= 32)
        for (int r = 0; r < R; ++r)
            total += __shfl(bnd, 32 + r, 64) - __shfl(bnd, r, 64);
    bool use_lds = (R <= 32) && (total <= WINCAP);   // block-uniform

    // wave's 2 queries
    float4 qva = qbuf[wave * 2],  qvb = qbuf[wave * 2 + 1];
    int oa = __float_as_int(qva.w), ob = __float_as_int(qvb.w);
    float qax = qva.x, qay = qva.y, qaz = qva.z;
    float qbx = qvb.x, qby = qvb.y, qbz = qvb.z;
    float sqa = np_self_dot(qax, qay, qaz);
    float sqb = np_self_dot(qbx, qby, qbz);
    unsigned long long ka = ~0ULL, kb = ~0ULL;

    if (use_lds) {
        // block-coop staging (coalesced per row; bnd identical across waves)
        int off = 0;
        for (int r = 0; r < R; ++r) {
            int Lr = __shfl(bnd, r, 64), Hr = __shfl(bnd, 32 + r, 64);
            int cnt = Hr - Lr;
            for (int j = tid; j < cnt; j += 256) win[off + j] = rs[Lr + j];
            off += cnt;
        }
        __syncthreads();

        if (off == 0) {                         // empty union box: samp bound
            float4 samp = rs[lane * SSTRIDE];
            EVALQ(samp, qax, qay, qaz, sqa, ka)
            EVALQ(samp, qbx, qby, qbz, sqb, kb)
        } else {
            int t = lane;
            if (t < off) {                       // one LDS read, two EVALs
                float4 rc = win[t];
                for (t += 64; t < off; t += 64) {
                    float4 rn = win[t];
                    EVALQ(rc, qax, qay, qaz, sqa, ka)
                    EVALQ(rc, qbx, qby, qbz, sqb, kb)
                    rc = rn;
                }
                EVALQ(rc, qax, qay, qaz, sqa, ka)
                EVALQ(rc, qbx, qby, qbz, sqb, kb)
            }
        }
        ka = wave_min_u64(ka);
        kb = wave_min_u64(kb);

        // certification vs the STAGED box; rare escape -> exact L2 W-box
        float Wa = sqrtf(invord((unsigned)(ka >> 32)) + MARGIN);
        float Wb = sqrtf(invord((unsigned)(kb >> 32)) + MARGIN);
        int txLa = cellC(qax - Wa), txRa = cellC(qax + Wa);
        int tyLa = cellC(qay - Wa), tyRa = cellC(qay + Wa);
        int txLb = cellC(qbx - Wb), txRb = cellC(qbx + Wb);
        int tyLb = cellC(qby - Wb), tyRb = cellC(qby + Wb);
        if (!(txLa >= xL && txRa <= xR && tyLa >= yL && tyRa <= yR)) {
            SCAN_RECT(txLa, txRa, tyLa, tyRa, qax, qay, qaz, sqa, ka)
            ka = wave_min_u64(ka);
        }
        if (!(txLb >= xL && txRb <= xR && tyLb >= yL && tyRb <= yR)) {
            SCAN_RECT(txLb, txRb, tyLb, tyRb, qbx, qby, qbz, sqb, kb)
            kb = wave_min_u64(kb);
        }
    } else {
        // fallback: r29's PROVEN per-wave 2-query path (own 5x5 seeds)
        float4 samp = rs[lane * SSTRIDE];
        int cxa = cellC(qax), cya = cellC(qay);
        int cxb = cellC(qbx), cyb = cellC(qby);
        int sxLa = cxa > 1 ? cxa-2 : 0, sxRa = cxa < NG-2 ? cxa+2 : NG-1;
        int syLa = cya > 1 ? cya-2 : 0, syRa = cya < NG-2 ? cya+2 : NG-1;
        int sxLb = cxb > 1 ? cxb-2 : 0, sxRb = cxb < NG-2 ? cxb+2 : NG-1;
        int syLb = cyb > 1 ? cyb-2 : 0, syRb = cyb < NG-2 ? cyb+2 : NG-1;
        int nrsA = sxRa - sxLa + 1, nrsB = sxRb - sxLb + 1;
        int xrA  = sxLa + (l31 < nrsA ? l31 : nrsA - 1);
        int xrB  = sxLb + (l31 < nrsB ? l31 : nrsB - 1);
        int colA = (lane < 32) ? syLa : (syRa + 1);
        int colB = (lane < 32) ? syLb : (syRb + 1);
        int bndA = cs[xrA * NG + colA];
        int bndB = cs[xrB * NG + colB];
        SCAN_ROWS32(bndA, nrsA, qax, qay, qaz, sqa, ka)
        SCAN_ROWS32(bndB, nrsB, qbx, qby, qbz, sqb, kb)
        EVALQ(samp, qax, qay, qaz, sqa, ka)
        EVALQ(samp, qbx, qby, qbz, sqb, kb)
        ka = wave_min_u64(ka);
        kb = wave_min_u64(kb);
        float Wa = sqrtf(invord((unsigned)(ka >> 32)) + MARGIN);
        float Wb = sqrtf(invord((unsigned)(kb >> 32)) + MARGIN);
        int txLa = cellC(qax - Wa), txRa = cellC(qax + Wa);
        int tyLa = cellC(qay - Wa), tyRa = cellC(qay + Wa);
        int txLb = cellC(qbx - Wb), txRb = cellC(qbx + Wb);
        int tyLb = cellC(qby - Wb), tyRb = cellC(qby + Wb);
        if (!(txLa >= sxLa && txRa <= sxRa && tyLa >= syLa && tyRa <= syRa)) {
            SCAN_RECT(txLa, txRa, tyLa, tyRa, qax, qay, qaz, sqa, ka)
            ka = wave_min_u64(ka);
        }
        if (!(txLb >= sxLb && txRb <= sxRb && tyLb >= syLb && tyRb <= syRb)) {
            SCAN_RECT(txLb, txRb, tyLb, tyRb, qbx, qby, qbz, sqb, kb)
            kb = wave_min_u64(kb);
        }
    }

    if (lane == 0) {
        out[dir * N_PTS + oa]       = invord((unsigned)(ka >> 32));
        out[(2 + dir) * N_PTS + oa] = (float)(unsigned)(ka & 0xFFFFFFFFu);
        out[dir * N_PTS + ob]       = invord((unsigned)(kb >> 32));
        out[(2 + dir) * N_PTS + ob] = (float)(unsigned)(kb & 0xFFFFFFFFu);
    }
}

// ---- fallback (tiny workspace): brute-force direct kernel (proven r2) ----
__device__ __forceinline__ float np_pair(float sq, float sr,
                                         float qx, float qy, float qz,
                                         float rx, float ry, float rz) {
    float zz = __fadd_rn(__fadd_rn(__fmul_rn(qx, rx), __fmul_rn(qy, ry)),
                         __fmul_rn(qz, rz));
    return __fsub_rn(__fadd_rn(sq, sr), __fadd_rn(zz, zz));
}

__global__ __launch_bounds__(256) void chamfer_direct_kernel(
    const float* __restrict__ preds, const float* __restrict__ gts,
    float* __restrict__ out)
{
    __shared__ float4 spts[256];
    int bid = blockIdx.x;
    int dir = bid / QB79;
    int qb  = bid - dir * QB79;
    int q   = qb * 256 + threadIdx.x;

    const float* qpts = (dir == 0) ? preds : gts;
    const float* rpts = (dir == 0) ? gts   : preds;

    int qc = (q < N_PTS) ? q : (N_PTS - 1);
    float qx = qpts[qc*3+0], qy = qpts[qc*3+1], qz = qpts[qc*3+2];
    float sq = np_self_dot(qx, qy, qz);
    float best = 3.4e38f;
    int   bidx = 0;

    for (int t = 0; t < N_PTS; t += 256) {
        int cnt = min(256, N_PTS - t);
        __syncthreads();
        if ((int)threadIdx.x < cnt) {
            int j = t + threadIdx.x;
            float rx = rpts[j*3+0], ry = rpts[j*3+1], rz = rpts[j*3+2];
            spts[threadIdx.x] = make_float4(rx, ry, rz, np_self_dot(rx, ry, rz));
        }
        __syncthreads();
        for (int k = 0; k < cnt; ++k) {
            float4 r = spts[k];
            float d = np_pair(sq, r.w, qx, qy, qz, r.x, r.y, r.z);
            if (d < best) { best = d; bidx = t + k; }
        }
    }
    if (q < N_PTS) {
        out[dir * N_PTS + q]       = best;
        out[(2 + dir) * N_PTS + q] = (float)bidx;
    }
}

extern "C" void kernel_launch(void* const* d_in, const int* in_sizes, int n_in,
                              void* d_out, int out_size, void* d_ws, size_t ws_size,
                              hipStream_t stream) {
    const float* preds = (const float*)d_in[0];  // [20000, 3]
    const float* gts   = (const float*)d_in[1];  // [1, 20000, 3]
    float* out = (float*)d_out;

    char* w = (char*)d_ws;
    size_t sorted_b = (size_t)2 * N_PTS * sizeof(float4);   // 640000
    size_t bstart_b = (size_t)2 * (NC + 1) * sizeof(int);   // 131080
    size_t cursor_b = (size_t)2 * NC * sizeof(int);         // 131072
    size_t need = sorted_b + bstart_b + cursor_b;

    if (ws_size >= need) {
        float4* sorted = (float4*)w;
        int* bstart = (int*)(w + sorted_b);
        int* cursor = (int*)(w + sorted_b + bstart_b);

        hipMemsetAsync(cursor, 0, cursor_b, stream);
        k_hist<<<(2 * N_PTS + 255) / 256, 256, 0, stream>>>(preds, gts, cursor);
        k_scan<<<2, 1024, 0, stream>>>(cursor, bstart);
        k_scatter<<<(2 * N_PTS + 255) / 256, 256, 0, stream>>>(
            preds, gts, cursor, sorted);
        k_main<<<2 * N_PTS / QPB, 256, 0, stream>>>(sorted, bstart, out);
    } else {
        chamfer_direct_kernel<<<2 * QB79, 256, 0, stream>>>(preds, gts, out);
    }
}